// Round 1
// baseline (522.268 us; speedup 1.0000x reference)
//
#include <hip/hip_runtime.h>
#include <hip/hip_bf16.h>
#include <math.h>

typedef __hip_bfloat16 bf16;
typedef __bf16  bf16x8  __attribute__((ext_vector_type(8)));
typedef float   floatx4 __attribute__((ext_vector_type(4)));

typedef const __attribute__((address_space(1))) void global_cv_t;
typedef __attribute__((address_space(3))) void       lds_v_t;

static __device__ __forceinline__ float bf2f(bf16 h) { return __bfloat162float(h); }
static __device__ __forceinline__ bf16  f2bf(float f) { return __float2bfloat16(f); }

__device__ __forceinline__ void load_lds16(const void* g, void* l) {
    // async global->LDS, 16B per lane; LDS dest = wave-uniform base + lane*16
    __builtin_amdgcn_global_load_lds((global_cv_t*)g, (lds_v_t*)l, 16, 0, 0);
}

// ---------------------------------------------------------------------------
// x (f32, 16M elems) -> bf16, vectorized
// ---------------------------------------------------------------------------
__global__ __launch_bounds__(256) void convx_k(const float4* __restrict__ in,
                                               bf16* __restrict__ out)
{
    const int i = blockIdx.x * 256 + threadIdx.x;   // 0 .. 4194303
    const float4 v = in[i];
    bf16* o = out + (size_t)i * 4;
    o[0] = f2bf(v.x); o[1] = f2bf(v.y); o[2] = f2bf(v.z); o[3] = f2bf(v.w);
}

// ---------------------------------------------------------------------------
// Transpose+convert 5x (1024x1024 f32): dst[n][k] = (bf16)src[k][n]
// ---------------------------------------------------------------------------
__global__ __launch_bounds__(256) void trc_k(
    const float* __restrict__ w0, const float* __restrict__ w1,
    const float* __restrict__ w2, const float* __restrict__ w3,
    const float* __restrict__ w4, bf16* __restrict__ dst)
{
    const float* src;
    switch (blockIdx.z) {
        case 0: src = w0; break;
        case 1: src = w1; break;
        case 2: src = w2; break;
        case 3: src = w3; break;
        default: src = w4; break;
    }
    bf16* d = dst + ((size_t)blockIdx.z << 20);
    __shared__ float tile[32][33];
    const int tx = threadIdx.x & 31;
    const int ty = threadIdx.x >> 5;   // 0..7
    const int bx = blockIdx.x * 32, by = blockIdx.y * 32;
#pragma unroll
    for (int j = 0; j < 32; j += 8)
        tile[ty + j][tx] = src[(size_t)(by + ty + j) * 1024 + bx + tx];
    __syncthreads();
#pragma unroll
    for (int j = 0; j < 32; j += 8)
        d[(size_t)(bx + ty + j) * 1024 + by + tx] = f2bf(tile[tx][ty + j]);
}

// ---------------------------------------------------------------------------
// 256x256-tile 8-phase GEMM (T2+T3+T4+T5). C[m][n] = sum_k A[m][k]*Bt[n][k]
// + bias[n], mode-dependent epilogue. A,Bt bf16; M=16384, N=1024, K=1024.
// 512 threads = 8 waves (2 wave-rows x 4 wave-cols); per-wave output 128x64
// (8x4 fragments of 16x16). BK=64; two K-tiles per loop iteration; 8 phases;
// counted vmcnt(4) at phases 4 and 8 only (never 0 in the main loop).
//
// LDS: lds[2 dbuf][A,B][256][64] bf16 = 128 KiB, double-buffered; K-granule
// XOR swizzle: LDS[row][slot] holds global granule slot^(row&7). Staging
// pre-swizzles the per-lane GLOBAL address (free, same 128B segment) so
// global_load_lds's linear lane->base+lane*16 mapping yields the swizzled
// layout; fragment ds_read_b128 then spreads 64 lanes over all banks 2-way.
//
// Staging schedule (iteration j computes kt0=2j from buf0, kt1=2j+1 from
// buf1; each phase stages 1 half-tile = 2 global_load_lds/wave):
//   P1: buf1.A-lo(kt1)  P2: buf1.A-hi(kt1)   [buf1.A freed at prev P8-end]
//   P3: buf0.B-lo(kt0+2) P4: buf0.B-hi(kt0+2)[buf0.B read entirely in P1]
//   P5: buf0.A-lo(kt0+2) P6: buf0.A-hi(kt0+2)[buf0.A freed at P4-end]
//   P7: buf1.B-lo(kt1+2) P8: buf1.B-hi(kt1+2)[buf1.B read entirely in P5]
// vmcnt(4) at P4-end guarantees buf1 complete (leaves P3,P4 in flight);
// vmcnt(4) at P8-end guarantees buf0 complete (leaves P7,P8 in flight).
// Last iteration peeled: stages only buf1.A(15), drains with vmcnt(0).
//
// modes: 0=tanh->Db  1=sigmoid*(1-auxf[row])->Db  2=plain->Db  3=gelu->Db
//        4=(+auxb residual)->Df (f32)
//        5=dual: blockIdx.y>=4 selects {WinT1->sigmoid->Db2}
// ---------------------------------------------------------------------------
__global__ __launch_bounds__(512, 2) void gemm8_k(
    const bf16* __restrict__ A, const bf16* __restrict__ Bt,
    const float* __restrict__ bias, const float* __restrict__ auxf,
    const bf16* __restrict__ auxb, bf16* __restrict__ Db,
    bf16* __restrict__ Db2, float* __restrict__ Df, const int mode)
{
    __shared__ alignas(16) bf16 lds[2][2][256][64];   // 128 KiB

    const int tid  = threadIdx.x;
    const int wave = tid >> 6;      // 0..7
    const int lane = tid & 63;
    const int quad = lane >> 4;     // 0..3
    const int l16  = lane & 15;
    const int swz  = l16 & 7;       // row-derived XOR key for fragment reads
    const int wm   = wave >> 2;     // wave row (128 rows)
    const int wn   = wave & 3;      // wave col (64 cols)
    const int bm   = blockIdx.x * 256;

    int bn, emode;
    const bf16* Bte = Bt;
    const float* biase = bias;
    bf16* Dbe = Db;
    if (mode == 5) {
        const int mat = blockIdx.y >> 2;          // 0: tanh/Win0, 1: sigmoid/Win1
        bn    = (blockIdx.y & 3) * 256;
        Bte   = Bt + ((size_t)mat << 20);
        biase = bias + (mat << 10);
        Dbe   = mat ? Db2 : Db;
        emode = mat ? 1 : 0;
    } else {
        bn = blockIdx.y * 256;
        emode = mode;
    }

    // staging: per half-tile (128 rows x 64 k), 2 loads/thread of 16B.
    // thread t covers chunk row t>>3 (0..63), swizzled k-granule (t&7)^(row&7).
    const int srow  = tid >> 3;                        // 0..63
    const int skoff = (((tid & 7) ^ (srow & 7)) << 3); // swizzled k elem-offset
    const bf16* gA = A   + (size_t)(bm + srow) * 1024 + skoff;
    const bf16* gB = Bte + (size_t)(bn + srow) * 1024 + skoff;

#define STAGE_A(BUF, H, KT) do {                                                  \
        load_lds16(gA + (size_t)((H) * 128) * 1024 + (KT) * 64,                   \
                   &lds[BUF][0][(H) * 128 + wave * 8][0]);                        \
        load_lds16(gA + (size_t)((H) * 128 + 64) * 1024 + (KT) * 64,              \
                   &lds[BUF][0][(H) * 128 + 64 + wave * 8][0]);                   \
    } while (0)
#define STAGE_B(BUF, H, KT) do {                                                  \
        load_lds16(gB + (size_t)((H) * 128) * 1024 + (KT) * 64,                   \
                   &lds[BUF][1][(H) * 128 + wave * 8][0]);                        \
        load_lds16(gB + (size_t)((H) * 128 + 64) * 1024 + (KT) * 64,              \
                   &lds[BUF][1][(H) * 128 + 64 + wave * 8][0]);                   \
    } while (0)
#define VMCNT4 asm volatile("s_waitcnt vmcnt(4)" ::: "memory")
#define VMCNT0 asm volatile("s_waitcnt vmcnt(0)" ::: "memory")

    floatx4 acc[8][4];
#pragma unroll
    for (int i = 0; i < 8; ++i)
#pragma unroll
        for (int jj = 0; jj < 4; ++jj)
            acc[i][jj] = (floatx4){0.f, 0.f, 0.f, 0.f};

    bf16x8 bfrag[4][2];   // all 4 n-frags x 2 k-slices, loaded at P0 of a tile
    bf16x8 afrag[2][2];   // 2 m-frags x 2 k-slices, reloaded each phase

    // Phase: {ds_read frags || stage 1 half-tile} -> barrier -> lgkmcnt(0) ->
    //        setprio(1) -> 16 MFMA -> setprio(0) -> [vmcnt] -> barrier.
#define PHASE(BUF, P, STAGE_STMT, WAIT_STMT)                                      \
    do {                                                                          \
        if ((P) == 0) {                                                           \
            _Pragma("unroll")                                                     \
            for (int fn_ = 0; fn_ < 4; ++fn_) {                                   \
                _Pragma("unroll")                                                 \
                for (int kk_ = 0; kk_ < 2; ++kk_)                                 \
                    bfrag[fn_][kk_] = *(const bf16x8*)&lds[BUF][1]                \
                        [wn * 64 + fn_ * 16 + l16]                                \
                        [((kk_ * 4 + quad) ^ swz) << 3];                          \
            }                                                                     \
        }                                                                         \
        _Pragma("unroll")                                                         \
        for (int fl_ = 0; fl_ < 2; ++fl_) {                                       \
            _Pragma("unroll")                                                     \
            for (int kk_ = 0; kk_ < 2; ++kk_)                                     \
                afrag[fl_][kk_] = *(const bf16x8*)&lds[BUF][0]                    \
                    [wm * 128 + ((P) * 2 + fl_) * 16 + l16]                       \
                    [((kk_ * 4 + quad) ^ swz) << 3];                              \
        }                                                                         \
        STAGE_STMT;                                                               \
        __builtin_amdgcn_s_barrier();                                             \
        asm volatile("s_waitcnt lgkmcnt(0)" ::: "memory");                        \
        __builtin_amdgcn_s_setprio(1);                                            \
        _Pragma("unroll")                                                         \
        for (int fl_ = 0; fl_ < 2; ++fl_) {                                       \
            _Pragma("unroll")                                                     \
            for (int fn_ = 0; fn_ < 4; ++fn_) {                                   \
                _Pragma("unroll")                                                 \
                for (int kk_ = 0; kk_ < 2; ++kk_)                                 \
                    acc[(P) * 2 + fl_][fn_] =                                     \
                        __builtin_amdgcn_mfma_f32_16x16x32_bf16(                  \
                            afrag[fl_][kk_], bfrag[fn_][kk_],                     \
                            acc[(P) * 2 + fl_][fn_], 0, 0, 0);                    \
            }                                                                     \
        }                                                                         \
        __builtin_amdgcn_s_setprio(0);                                            \
        WAIT_STMT;                                                                \
        __builtin_amdgcn_s_barrier();                                             \
    } while (0)

    // prologue: buf0 <- kt0 (A+B), buf1 <- kt1 (B only; A arrives at P1-P2).
    STAGE_A(0, 0, 0); STAGE_A(0, 1, 0);
    STAGE_B(0, 0, 0); STAGE_B(0, 1, 0);
    STAGE_B(1, 0, 1); STAGE_B(1, 1, 1);
    asm volatile("s_waitcnt vmcnt(4)" ::: "memory");   // buf0 landed; buf1.B in flight
    __builtin_amdgcn_s_barrier();

#pragma unroll 1
    for (int it = 0; it < 7; ++it) {
        const int ka = 2 * it + 1;   // buf1 A tile (this iteration's tile1)
        const int kb = 2 * it + 2;   // buf0 next tile
        const int kc = 2 * it + 3;   // buf1 next B tile
        PHASE(0, 0, STAGE_A(1, 0, ka), (void)0);
        PHASE(0, 1, STAGE_A(1, 1, ka), (void)0);
        PHASE(0, 2, STAGE_B(0, 0, kb), (void)0);
        PHASE(0, 3, STAGE_B(0, 1, kb), VMCNT4);
        PHASE(1, 0, STAGE_A(0, 0, kb), (void)0);
        PHASE(1, 1, STAGE_A(0, 1, kb), (void)0);
        PHASE(1, 2, STAGE_B(1, 0, kc), (void)0);
        PHASE(1, 3, STAGE_B(1, 1, kc), VMCNT4);
    }
    // peeled epilogue: kt=14 (buf0), kt=15 (buf1); no staging past K.
    PHASE(0, 0, STAGE_A(1, 0, 15), (void)0);
    PHASE(0, 1, STAGE_A(1, 1, 15), (void)0);
    PHASE(0, 2, (void)0, (void)0);
    PHASE(0, 3, (void)0, VMCNT0);
    PHASE(1, 0, (void)0, (void)0);
    PHASE(1, 1, (void)0, (void)0);
    PHASE(1, 2, (void)0, (void)0);
    PHASE(1, 3, (void)0, (void)0);

#undef PHASE
#undef STAGE_A
#undef STAGE_B
#undef VMCNT4
#undef VMCNT0

    // epilogue. C/D layout: col = lane&15, row = quad*4 + reg (m89-verified)
    float bv[4];
#pragma unroll
    for (int fn = 0; fn < 4; ++fn)
        bv[fn] = biase[bn + wn * 64 + fn * 16 + l16];

#pragma unroll
    for (int fm = 0; fm < 8; ++fm) {
#pragma unroll
        for (int r = 0; r < 4; ++r) {
            const int gm = bm + wm * 128 + fm * 16 + quad * 4 + r;
            const size_t rowoff = (size_t)gm << 10;
            float rowmul = 1.f;
            if (emode == 1) rowmul = 1.f - auxf[gm];
#pragma unroll
            for (int fn = 0; fn < 4; ++fn) {
                const int gn = bn + wn * 64 + fn * 16 + l16;
                float val = acc[fm][fn][r] + bv[fn];
                if (emode == 0)      val = tanhf(val);
                else if (emode == 1) val = rowmul / (1.f + expf(-val));
                else if (emode == 3) val = 0.5f * val * (1.f + erff(val * 0.70710678118654752f));
                if (emode == 4) {
                    val += bf2f(auxb[rowoff + gn]);
                    Df[rowoff + gn] = val;
                } else {
                    Dbe[rowoff + gn] = f2bf(val);
                }
            }
        }
    }
}

// ---------------------------------------------------------------------------
// Chunked linear-recurrence scan: h[t] = f[t]*h[t-1] + (1-f[t])*v[t].
// T=4096 split into 64 chunks of 64. 4096 channels (b,d).
// ---------------------------------------------------------------------------
__global__ __launch_bounds__(256) void scan1_k(
    const bf16* __restrict__ v, const bf16* __restrict__ f,
    float* __restrict__ Ac, float* __restrict__ Bc)
{
    const int idx = blockIdx.x * 256 + threadIdx.x;   // 0..262143
    const int ch = idx & 4095;        // b*1024 + d
    const int c  = idx >> 12;         // chunk 0..63
    const int b  = ch >> 10, d = ch & 1023;
    const size_t base = ((size_t)(b * 4096 + c * 64) << 10) + d;
    float a = 1.f, hb = 0.f;
#pragma unroll 8
    for (int i = 0; i < 64; ++i) {
        const size_t o = base + ((size_t)i << 10);
        const float ft = bf2f(f[o]);
        const float vt = bf2f(v[o]);
        hb = fmaf(ft, hb, (1.f - ft) * vt);
        a *= ft;
    }
    Ac[c * 4096 + ch] = a;
    Bc[c * 4096 + ch] = hb;
}

__global__ __launch_bounds__(256) void scanmid_k(
    const float* __restrict__ Ac, const float* __restrict__ Bc,
    const float* __restrict__ hidden, float* __restrict__ Hin)
{
    const int ch = blockIdx.x * 256 + threadIdx.x;    // 0..4095
    float h = hidden[ch];
#pragma unroll 8
    for (int c = 0; c < 64; ++c) {
        Hin[c * 4096 + ch] = h;
        h = fmaf(Ac[c * 4096 + ch], h, Bc[c * 4096 + ch]);
    }
}

__global__ __launch_bounds__(256) void scan2_k(
    const bf16* __restrict__ v, const bf16* __restrict__ f,
    const float* __restrict__ Hin, bf16* __restrict__ hs,
    float* __restrict__ hT)
{
    const int idx = blockIdx.x * 256 + threadIdx.x;
    const int ch = idx & 4095;
    const int c  = idx >> 12;
    const int b  = ch >> 10, d = ch & 1023;
    const size_t base = ((size_t)(b * 4096 + c * 64) << 10) + d;
    float h = Hin[c * 4096 + ch];
#pragma unroll 8
    for (int i = 0; i < 64; ++i) {
        const size_t o = base + ((size_t)i << 10);
        const float ft = bf2f(f[o]);
        const float vt = bf2f(v[o]);
        h = fmaf(ft, h, (1.f - ft) * vt);
        hs[o] = f2bf(h);
    }
    if (c == 63) hT[ch] = h;
}

// ---------------------------------------------------------------------------
// LayerNorm over D=1024 (f32 in-place on d_out), one block per row.
// ---------------------------------------------------------------------------
__global__ __launch_bounds__(256) void ln_k(
    float* __restrict__ s, const float* __restrict__ g,
    const float* __restrict__ b)
{
    const int row = blockIdx.x;
    const int tid = threadIdx.x;
    const size_t off = (size_t)row << 10;
    const float4 xv = ((const float4*)(s + off))[tid];
    float sum = xv.x + xv.y + xv.z + xv.w;
    float sq  = xv.x * xv.x + xv.y * xv.y + xv.z * xv.z + xv.w * xv.w;
#pragma unroll
    for (int o = 32; o > 0; o >>= 1) {
        sum += __shfl_down(sum, o, 64);
        sq  += __shfl_down(sq,  o, 64);
    }
    __shared__ float s1[4], s2[4];
    if ((tid & 63) == 0) { s1[tid >> 6] = sum; s2[tid >> 6] = sq; }
    __syncthreads();
    sum = s1[0] + s1[1] + s1[2] + s1[3];
    sq  = s2[0] + s2[1] + s2[2] + s2[3];
    const float mean = sum * (1.f / 1024.f);
    const float var  = sq * (1.f / 1024.f) - mean * mean;
    const float rstd = rsqrtf(var + 1e-5f);
    const float4 gv = ((const float4*)g)[tid];
    const float4 bv = ((const float4*)b)[tid];
    float4 y;
    y.x = (xv.x - mean) * rstd * gv.x + bv.x;
    y.y = (xv.y - mean) * rstd * gv.y + bv.y;
    y.z = (xv.z - mean) * rstd * gv.z + bv.z;
    y.w = (xv.w - mean) * rstd * gv.w + bv.w;
    ((float4*)(s + off))[tid] = y;
}

// ---------------------------------------------------------------------------
extern "C" void kernel_launch(void* const* d_in, const int* in_sizes, int n_in,
                              void* d_out, int out_size, void* d_ws, size_t ws_size,
                              hipStream_t stream)
{
    const float* x         = (const float*)d_in[0];   // (4,4096,1024)
    const float* hidden    = (const float*)d_in[1];   // (4,1,1024)
    const float* rnn_start = (const float*)d_in[2];   // (4,4096,1)
    const float* Win       = (const float*)d_in[3];   // (2,1024,1024)
    const float* bin_      = (const float*)d_in[4];   // (2,1024)
    const float* Wout      = (const float*)d_in[5];
    const float* bout      = (const float*)d_in[6];
    const float* W1        = (const float*)d_in[7];
    const float* b1        = (const float*)d_in[8];
    const float* W2        = (const float*)d_in[9];
    const float* b2        = (const float*)d_in[10];
    const float* ln_g      = (const float*)d_in[11];
    const float* ln_b      = (const float*)d_in[12];
    float* out = (float*)d_out;                // out(16777216 f32) ++ hidden_new(4096 f32)
    float* hT  = out + (1u << 24);

    // workspace layout
    char* p = (char*)d_ws;
    bf16* Wt    = (bf16*)p;                    p += 5ull * (1u << 20) * sizeof(bf16);
    bf16* slotA = (bf16*)p;                    p += (1ull << 24) * sizeof(bf16);  // xb, later hs
    bf16* slotB = (bf16*)p;                    p += (1ull << 24) * sizeof(bf16);  // v,  later outp
    bf16* slotC = (bf16*)p;                    p += (1ull << 24) * sizeof(bf16);  // f,  later x_
    float* Ac  = (float*)p;                    p += (1ull << 18) * sizeof(float);
    float* Bc  = (float*)p;                    p += (1ull << 18) * sizeof(float);
    float* Hin = (float*)p;                    p += (1ull << 18) * sizeof(float);

    bf16* WoutT = Wt + 2u * (1u << 20);
    bf16* W1T   = Wt + 3u * (1u << 20);
    bf16* W2T   = Wt + 4u * (1u << 20);

    convx_k<<<16384, 256, 0, stream>>>((const float4*)x, slotA);
    trc_k<<<dim3(32, 32, 5), 256, 0, stream>>>(Win, Win + (1u << 20), Wout, W1, W2, Wt);

    // merged dual GEMM: y>=4 -> Win1/sigmoid.  v -> slotB, f -> slotC
    gemm8_k<<<dim3(64, 8), 512, 0, stream>>>(slotA, Wt, bin_, rnn_start, nullptr,
                                             slotB, slotC, nullptr, 5);

    // chunked scan: hs -> slotA (xb dead), hT -> d_out tail
    scan1_k<<<1024, 256, 0, stream>>>(slotB, slotC, Ac, Bc);
    scanmid_k<<<16, 256, 0, stream>>>(Ac, Bc, hidden, Hin);
    scan2_k<<<1024, 256, 0, stream>>>(slotB, slotC, Hin, slotA, hT);

    // outp = hs@Wout + bout (-> slotB); x_ = gelu(outp@W1+b1) (-> slotC);
    // s = x_@W2 + b2 + outp -> f32 in d_out
    gemm8_k<<<dim3(64, 4), 512, 0, stream>>>(slotA, WoutT, bout, nullptr, nullptr,
                                             slotB, nullptr, nullptr, 2);
    gemm8_k<<<dim3(64, 4), 512, 0, stream>>>(slotB, W1T,   b1,   nullptr, nullptr,
                                             slotC, nullptr, nullptr, 3);
    gemm8_k<<<dim3(64, 4), 512, 0, stream>>>(slotC, W2T,   b2,   nullptr, slotB,
                                             nullptr, nullptr, out, 4);

    ln_k<<<16384, 256, 0, stream>>>(out, ln_g, ln_b);
}

// Round 2
// 516.584 us; speedup vs baseline: 1.0110x; 1.0110x over previous
//
#include <hip/hip_runtime.h>
#include <hip/hip_bf16.h>
#include <math.h>

typedef __hip_bfloat16 bf16;
typedef __bf16  bf16x8  __attribute__((ext_vector_type(8)));
typedef float   floatx4 __attribute__((ext_vector_type(4)));

typedef const __attribute__((address_space(1))) void global_cv_t;
typedef __attribute__((address_space(3))) void       lds_v_t;

static __device__ __forceinline__ float bf2f(bf16 h) { return __bfloat162float(h); }
static __device__ __forceinline__ bf16  f2bf(float f) { return __float2bfloat16(f); }

__device__ __forceinline__ void load_lds16(const void* g, void* l) {
    // async global->LDS, 16B per lane; LDS dest = wave-uniform base + lane*16
    __builtin_amdgcn_global_load_lds((global_cv_t*)g, (lds_v_t*)l, 16, 0, 0);
}

// ---------------------------------------------------------------------------
// x (f32, 16M elems) -> bf16, vectorized
// ---------------------------------------------------------------------------
__global__ __launch_bounds__(256) void convx_k(const float4* __restrict__ in,
                                               bf16* __restrict__ out)
{
    const int i = blockIdx.x * 256 + threadIdx.x;   // 0 .. 4194303
    const float4 v = in[i];
    bf16* o = out + (size_t)i * 4;
    o[0] = f2bf(v.x); o[1] = f2bf(v.y); o[2] = f2bf(v.z); o[3] = f2bf(v.w);
}

// ---------------------------------------------------------------------------
// Transpose+convert 5x (1024x1024 f32): dst[n][k] = (bf16)src[k][n]
// ---------------------------------------------------------------------------
__global__ __launch_bounds__(256) void trc_k(
    const float* __restrict__ w0, const float* __restrict__ w1,
    const float* __restrict__ w2, const float* __restrict__ w3,
    const float* __restrict__ w4, bf16* __restrict__ dst)
{
    const float* src;
    switch (blockIdx.z) {
        case 0: src = w0; break;
        case 1: src = w1; break;
        case 2: src = w2; break;
        case 3: src = w3; break;
        default: src = w4; break;
    }
    bf16* d = dst + ((size_t)blockIdx.z << 20);
    __shared__ float tile[32][33];
    const int tx = threadIdx.x & 31;
    const int ty = threadIdx.x >> 5;   // 0..7
    const int bx = blockIdx.x * 32, by = blockIdx.y * 32;
#pragma unroll
    for (int j = 0; j < 32; j += 8)
        tile[ty + j][tx] = src[(size_t)(by + ty + j) * 1024 + bx + tx];
    __syncthreads();
#pragma unroll
    for (int j = 0; j < 32; j += 8)
        d[(size_t)(bx + ty + j) * 1024 + by + tx] = f2bf(tile[tx][ty + j]);
}

// ---------------------------------------------------------------------------
// 256x256-tile 8-phase GEMM (T2+T3+T4+T5). C[m][n] = sum_k A[m][k]*Bt[n][k]
// + bias[n], mode-dependent epilogue. A,Bt bf16; M=16384, N=1024, K=1024.
// 512 threads = 8 waves (2 wave-rows x 4 wave-cols); per-wave output 128x64
// (8x4 fragments of 16x16). BK=64; two K-tiles per loop iteration; 8 phases;
// counted vmcnt(4) at phases 4 and 8 only (never 0 in the main loop).
//
// NOTE (round-2 fix): all s_waitcnt inline asms are BARE — no "memory"
// clobber. A memory-clobbered asm is mayLoad|mayStore with no MMOs, so
// SIInsertWaitcnts conservatively drains outstanding global_load_lds
// (LDS-writing VMEM) before EVERY such asm -> the counted-vmcnt pipeline
// collapses to one full HBM-latency stall per phase (observed: 141us,
// MfmaUtil 19.5%). The proven m201 template uses bare asm. Ordering safety
// without the clobber: barriers/DMA-intrinsics/volatile-asm are all
// side-effecting at MIR level (memory ops don't cross them), and the
// compiler still inserts precise lgkmcnt waits for its own ds_reads before
// each MFMA use. The DMA->ds_read dependency is carried by OUR vmcnt
// schedule, verified: at each VMCNT4 the 8 oldest (retired) loads are
// exactly the buffer consumed in the next phase.
//
// LDS: lds[2 dbuf][A,B][256][64] bf16 = 128 KiB, double-buffered; K-granule
// XOR swizzle: LDS[row][slot] holds global granule slot^(row&7). Staging
// pre-swizzles the per-lane GLOBAL address (free, same 128B segment) so
// global_load_lds's linear lane->base+lane*16 mapping yields the swizzled
// layout; fragment ds_read_b128 then spreads 64 lanes over all banks 2-way.
//
// Staging schedule (iteration j computes kt0=2j from buf0, kt1=2j+1 from
// buf1; each phase stages 1 half-tile = 2 global_load_lds/wave):
//   P1: buf1.A-lo(kt1)  P2: buf1.A-hi(kt1)   [buf1.A freed at prev P8-end]
//   P3: buf0.B-lo(kt0+2) P4: buf0.B-hi(kt0+2)[buf0.B read entirely in P1]
//   P5: buf0.A-lo(kt0+2) P6: buf0.A-hi(kt0+2)[buf0.A freed at P4-end]
//   P7: buf1.B-lo(kt1+2) P8: buf1.B-hi(kt1+2)[buf1.B read entirely in P5]
// vmcnt(4) at P4-end guarantees buf1 complete (leaves P3,P4 in flight);
// vmcnt(4) at P8-end guarantees buf0 complete (leaves P7,P8 in flight).
// Last iteration peeled: stages only buf1.A(15), drains with vmcnt(0).
//
// modes: 0=tanh->Db  1=sigmoid*(1-auxf[row])->Db  2=plain->Db  3=gelu->Db
//        4=(+auxb residual)->Df (f32)
//        5=dual: blockIdx.y>=4 selects {WinT1->sigmoid->Db2}
// ---------------------------------------------------------------------------
__global__ __launch_bounds__(512, 2) void gemm8_k(
    const bf16* __restrict__ A, const bf16* __restrict__ Bt,
    const float* __restrict__ bias, const float* __restrict__ auxf,
    const bf16* __restrict__ auxb, bf16* __restrict__ Db,
    bf16* __restrict__ Db2, float* __restrict__ Df, const int mode)
{
    __shared__ alignas(16) bf16 lds[2][2][256][64];   // 128 KiB

    const int tid  = threadIdx.x;
    const int wave = tid >> 6;      // 0..7
    const int lane = tid & 63;
    const int quad = lane >> 4;     // 0..3
    const int l16  = lane & 15;
    const int swz  = l16 & 7;       // row-derived XOR key for fragment reads
    const int wm   = wave >> 2;     // wave row (128 rows)
    const int wn   = wave & 3;      // wave col (64 cols)
    const int bm   = blockIdx.x * 256;

    int bn, emode;
    const bf16* Bte = Bt;
    const float* biase = bias;
    bf16* Dbe = Db;
    if (mode == 5) {
        const int mat = blockIdx.y >> 2;          // 0: tanh/Win0, 1: sigmoid/Win1
        bn    = (blockIdx.y & 3) * 256;
        Bte   = Bt + ((size_t)mat << 20);
        biase = bias + (mat << 10);
        Dbe   = mat ? Db2 : Db;
        emode = mat ? 1 : 0;
    } else {
        bn = blockIdx.y * 256;
        emode = mode;
    }

    // staging: per half-tile (128 rows x 64 k), 2 loads/thread of 16B.
    // thread t covers chunk row t>>3 (0..63), swizzled k-granule (t&7)^(row&7).
    const int srow  = tid >> 3;                        // 0..63
    const int skoff = (((tid & 7) ^ (srow & 7)) << 3); // swizzled k elem-offset
    const bf16* gA = A   + (size_t)(bm + srow) * 1024 + skoff;
    const bf16* gB = Bte + (size_t)(bn + srow) * 1024 + skoff;

#define STAGE_A(BUF, H, KT) do {                                                  \
        load_lds16(gA + (size_t)((H) * 128) * 1024 + (KT) * 64,                   \
                   &lds[BUF][0][(H) * 128 + wave * 8][0]);                        \
        load_lds16(gA + (size_t)((H) * 128 + 64) * 1024 + (KT) * 64,              \
                   &lds[BUF][0][(H) * 128 + 64 + wave * 8][0]);                   \
    } while (0)
#define STAGE_B(BUF, H, KT) do {                                                  \
        load_lds16(gB + (size_t)((H) * 128) * 1024 + (KT) * 64,                   \
                   &lds[BUF][1][(H) * 128 + wave * 8][0]);                        \
        load_lds16(gB + (size_t)((H) * 128 + 64) * 1024 + (KT) * 64,              \
                   &lds[BUF][1][(H) * 128 + 64 + wave * 8][0]);                   \
    } while (0)
#define VMCNT4 asm volatile("s_waitcnt vmcnt(4)")
#define VMCNT0 asm volatile("s_waitcnt vmcnt(0)")

    floatx4 acc[8][4];
#pragma unroll
    for (int i = 0; i < 8; ++i)
#pragma unroll
        for (int jj = 0; jj < 4; ++jj)
            acc[i][jj] = (floatx4){0.f, 0.f, 0.f, 0.f};

    bf16x8 bfrag[4][2];   // all 4 n-frags x 2 k-slices, loaded at P0 of a tile
    bf16x8 afrag[2][2];   // 2 m-frags x 2 k-slices, reloaded each phase

    // Phase: {ds_read frags || stage 1 half-tile} -> barrier -> lgkmcnt(0) ->
    //        setprio(1) -> 16 MFMA -> setprio(0) -> [vmcnt] -> barrier.
#define PHASE(BUF, P, STAGE_STMT, WAIT_STMT)                                      \
    do {                                                                          \
        if ((P) == 0) {                                                           \
            _Pragma("unroll")                                                     \
            for (int fn_ = 0; fn_ < 4; ++fn_) {                                   \
                _Pragma("unroll")                                                 \
                for (int kk_ = 0; kk_ < 2; ++kk_)                                 \
                    bfrag[fn_][kk_] = *(const bf16x8*)&lds[BUF][1]                \
                        [wn * 64 + fn_ * 16 + l16]                                \
                        [((kk_ * 4 + quad) ^ swz) << 3];                          \
            }                                                                     \
        }                                                                         \
        _Pragma("unroll")                                                         \
        for (int fl_ = 0; fl_ < 2; ++fl_) {                                       \
            _Pragma("unroll")                                                     \
            for (int kk_ = 0; kk_ < 2; ++kk_)                                     \
                afrag[fl_][kk_] = *(const bf16x8*)&lds[BUF][0]                    \
                    [wm * 128 + ((P) * 2 + fl_) * 16 + l16]                       \
                    [((kk_ * 4 + quad) ^ swz) << 3];                              \
        }                                                                         \
        STAGE_STMT;                                                               \
        __builtin_amdgcn_s_barrier();                                             \
        asm volatile("s_waitcnt lgkmcnt(0)");                                     \
        __builtin_amdgcn_s_setprio(1);                                            \
        _Pragma("unroll")                                                         \
        for (int fl_ = 0; fl_ < 2; ++fl_) {                                       \
            _Pragma("unroll")                                                     \
            for (int fn_ = 0; fn_ < 4; ++fn_) {                                   \
                _Pragma("unroll")                                                 \
                for (int kk_ = 0; kk_ < 2; ++kk_)                                 \
                    acc[(P) * 2 + fl_][fn_] =                                     \
                        __builtin_amdgcn_mfma_f32_16x16x32_bf16(                  \
                            afrag[fl_][kk_], bfrag[fn_][kk_],                     \
                            acc[(P) * 2 + fl_][fn_], 0, 0, 0);                    \
            }                                                                     \
        }                                                                         \
        __builtin_amdgcn_s_setprio(0);                                            \
        WAIT_STMT;                                                                \
        __builtin_amdgcn_s_barrier();                                             \
    } while (0)

    // prologue: buf0 <- kt0 (A+B), buf1 <- kt1 (B only; A arrives at P1-P2).
    STAGE_A(0, 0, 0); STAGE_A(0, 1, 0);
    STAGE_B(0, 0, 0); STAGE_B(0, 1, 0);
    STAGE_B(1, 0, 1); STAGE_B(1, 1, 1);
    asm volatile("s_waitcnt vmcnt(4)");   // buf0 landed; buf1.B in flight
    __builtin_amdgcn_s_barrier();

#pragma unroll 1
    for (int it = 0; it < 7; ++it) {
        const int ka = 2 * it + 1;   // buf1 A tile (this iteration's tile1)
        const int kb = 2 * it + 2;   // buf0 next tile
        const int kc = 2 * it + 3;   // buf1 next B tile
        PHASE(0, 0, STAGE_A(1, 0, ka), (void)0);
        PHASE(0, 1, STAGE_A(1, 1, ka), (void)0);
        PHASE(0, 2, STAGE_B(0, 0, kb), (void)0);
        PHASE(0, 3, STAGE_B(0, 1, kb), VMCNT4);
        PHASE(1, 0, STAGE_A(0, 0, kb), (void)0);
        PHASE(1, 1, STAGE_A(0, 1, kb), (void)0);
        PHASE(1, 2, STAGE_B(1, 0, kc), (void)0);
        PHASE(1, 3, STAGE_B(1, 1, kc), VMCNT4);
    }
    // peeled epilogue: kt=14 (buf0), kt=15 (buf1); no staging past K.
    PHASE(0, 0, STAGE_A(1, 0, 15), (void)0);
    PHASE(0, 1, STAGE_A(1, 1, 15), (void)0);
    PHASE(0, 2, (void)0, (void)0);
    PHASE(0, 3, (void)0, VMCNT0);
    PHASE(1, 0, (void)0, (void)0);
    PHASE(1, 1, (void)0, (void)0);
    PHASE(1, 2, (void)0, (void)0);
    PHASE(1, 3, (void)0, (void)0);

#undef PHASE
#undef STAGE_A
#undef STAGE_B
#undef VMCNT4
#undef VMCNT0

    // epilogue. C/D layout: col = lane&15, row = quad*4 + reg (m89-verified)
    float bv[4];
#pragma unroll
    for (int fn = 0; fn < 4; ++fn)
        bv[fn] = biase[bn + wn * 64 + fn * 16 + l16];

#pragma unroll
    for (int fm = 0; fm < 8; ++fm) {
#pragma unroll
        for (int r = 0; r < 4; ++r) {
            const int gm = bm + wm * 128 + fm * 16 + quad * 4 + r;
            const size_t rowoff = (size_t)gm << 10;
            float rowmul = 1.f;
            if (emode == 1) rowmul = 1.f - auxf[gm];
#pragma unroll
            for (int fn = 0; fn < 4; ++fn) {
                const int gn = bn + wn * 64 + fn * 16 + l16;
                float val = acc[fm][fn][r] + bv[fn];
                if (emode == 0)      val = tanhf(val);
                else if (emode == 1) val = rowmul / (1.f + expf(-val));
                else if (emode == 3) val = 0.5f * val * (1.f + erff(val * 0.70710678118654752f));
                if (emode == 4) {
                    val += bf2f(auxb[rowoff + gn]);
                    Df[rowoff + gn] = val;
                } else {
                    Dbe[rowoff + gn] = f2bf(val);
                }
            }
        }
    }
}

// ---------------------------------------------------------------------------
// Chunked linear-recurrence scan: h[t] = f[t]*h[t-1] + (1-f[t])*v[t].
// T=4096 split into 64 chunks of 64. 4096 channels (b,d).
// ---------------------------------------------------------------------------
__global__ __launch_bounds__(256) void scan1_k(
    const bf16* __restrict__ v, const bf16* __restrict__ f,
    float* __restrict__ Ac, float* __restrict__ Bc)
{
    const int idx = blockIdx.x * 256 + threadIdx.x;   // 0..262143
    const int ch = idx & 4095;        // b*1024 + d
    const int c  = idx >> 12;         // chunk 0..63
    const int b  = ch >> 10, d = ch & 1023;
    const size_t base = ((size_t)(b * 4096 + c * 64) << 10) + d;
    float a = 1.f, hb = 0.f;
#pragma unroll 8
    for (int i = 0; i < 64; ++i) {
        const size_t o = base + ((size_t)i << 10);
        const float ft = bf2f(f[o]);
        const float vt = bf2f(v[o]);
        hb = fmaf(ft, hb, (1.f - ft) * vt);
        a *= ft;
    }
    Ac[c * 4096 + ch] = a;
    Bc[c * 4096 + ch] = hb;
}

__global__ __launch_bounds__(256) void scanmid_k(
    const float* __restrict__ Ac, const float* __restrict__ Bc,
    const float* __restrict__ hidden, float* __restrict__ Hin)
{
    const int ch = blockIdx.x * 256 + threadIdx.x;    // 0..4095
    float h = hidden[ch];
#pragma unroll 8
    for (int c = 0; c < 64; ++c) {
        Hin[c * 4096 + ch] = h;
        h = fmaf(Ac[c * 4096 + ch], h, Bc[c * 4096 + ch]);
    }
}

__global__ __launch_bounds__(256) void scan2_k(
    const bf16* __restrict__ v, const bf16* __restrict__ f,
    const float* __restrict__ Hin, bf16* __restrict__ hs,
    float* __restrict__ hT)
{
    const int idx = blockIdx.x * 256 + threadIdx.x;
    const int ch = idx & 4095;
    const int c  = idx >> 12;
    const int b  = ch >> 10, d = ch & 1023;
    const size_t base = ((size_t)(b * 4096 + c * 64) << 10) + d;
    float h = Hin[c * 4096 + ch];
#pragma unroll 8
    for (int i = 0; i < 64; ++i) {
        const size_t o = base + ((size_t)i << 10);
        const float ft = bf2f(f[o]);
        const float vt = bf2f(v[o]);
        h = fmaf(ft, h, (1.f - ft) * vt);
        hs[o] = f2bf(h);
    }
    if (c == 63) hT[ch] = h;
}

// ---------------------------------------------------------------------------
// LayerNorm over D=1024 (f32 in-place on d_out), one block per row.
// ---------------------------------------------------------------------------
__global__ __launch_bounds__(256) void ln_k(
    float* __restrict__ s, const float* __restrict__ g,
    const float* __restrict__ b)
{
    const int row = blockIdx.x;
    const int tid = threadIdx.x;
    const size_t off = (size_t)row << 10;
    const float4 xv = ((const float4*)(s + off))[tid];
    float sum = xv.x + xv.y + xv.z + xv.w;
    float sq  = xv.x * xv.x + xv.y * xv.y + xv.z * xv.z + xv.w * xv.w;
#pragma unroll
    for (int o = 32; o > 0; o >>= 1) {
        sum += __shfl_down(sum, o, 64);
        sq  += __shfl_down(sq,  o, 64);
    }
    __shared__ float s1[4], s2[4];
    if ((tid & 63) == 0) { s1[tid >> 6] = sum; s2[tid >> 6] = sq; }
    __syncthreads();
    sum = s1[0] + s1[1] + s1[2] + s1[3];
    sq  = s2[0] + s2[1] + s2[2] + s2[3];
    const float mean = sum * (1.f / 1024.f);
    const float var  = sq * (1.f / 1024.f) - mean * mean;
    const float rstd = rsqrtf(var + 1e-5f);
    const float4 gv = ((const float4*)g)[tid];
    const float4 bv = ((const float4*)b)[tid];
    float4 y;
    y.x = (xv.x - mean) * rstd * gv.x + bv.x;
    y.y = (xv.y - mean) * rstd * gv.y + bv.y;
    y.z = (xv.z - mean) * rstd * gv.z + bv.z;
    y.w = (xv.w - mean) * rstd * gv.w + bv.w;
    ((float4*)(s + off))[tid] = y;
}

// ---------------------------------------------------------------------------
extern "C" void kernel_launch(void* const* d_in, const int* in_sizes, int n_in,
                              void* d_out, int out_size, void* d_ws, size_t ws_size,
                              hipStream_t stream)
{
    const float* x         = (const float*)d_in[0];   // (4,4096,1024)
    const float* hidden    = (const float*)d_in[1];   // (4,1,1024)
    const float* rnn_start = (const float*)d_in[2];   // (4,4096,1)
    const float* Win       = (const float*)d_in[3];   // (2,1024,1024)
    const float* bin_      = (const float*)d_in[4];   // (2,1024)
    const float* Wout      = (const float*)d_in[5];
    const float* bout      = (const float*)d_in[6];
    const float* W1        = (const float*)d_in[7];
    const float* b1        = (const float*)d_in[8];
    const float* W2        = (const float*)d_in[9];
    const float* b2        = (const float*)d_in[10];
    const float* ln_g      = (const float*)d_in[11];
    const float* ln_b      = (const float*)d_in[12];
    float* out = (float*)d_out;                // out(16777216 f32) ++ hidden_new(4096 f32)
    float* hT  = out + (1u << 24);

    // workspace layout
    char* p = (char*)d_ws;
    bf16* Wt    = (bf16*)p;                    p += 5ull * (1u << 20) * sizeof(bf16);
    bf16* slotA = (bf16*)p;                    p += (1ull << 24) * sizeof(bf16);  // xb, later hs
    bf16* slotB = (bf16*)p;                    p += (1ull << 24) * sizeof(bf16);  // v,  later outp
    bf16* slotC = (bf16*)p;                    p += (1ull << 24) * sizeof(bf16);  // f,  later x_
    float* Ac  = (float*)p;                    p += (1ull << 18) * sizeof(float);
    float* Bc  = (float*)p;                    p += (1ull << 18) * sizeof(float);
    float* Hin = (float*)p;                    p += (1ull << 18) * sizeof(float);

    bf16* WoutT = Wt + 2u * (1u << 20);
    bf16* W1T   = Wt + 3u * (1u << 20);
    bf16* W2T   = Wt + 4u * (1u << 20);

    convx_k<<<16384, 256, 0, stream>>>((const float4*)x, slotA);
    trc_k<<<dim3(32, 32, 5), 256, 0, stream>>>(Win, Win + (1u << 20), Wout, W1, W2, Wt);

    // merged dual GEMM: y>=4 -> Win1/sigmoid.  v -> slotB, f -> slotC
    gemm8_k<<<dim3(64, 8), 512, 0, stream>>>(slotA, Wt, bin_, rnn_start, nullptr,
                                             slotB, slotC, nullptr, 5);

    // chunked scan: hs -> slotA (xb dead), hT -> d_out tail
    scan1_k<<<1024, 256, 0, stream>>>(slotB, slotC, Ac, Bc);
    scanmid_k<<<16, 256, 0, stream>>>(Ac, Bc, hidden, Hin);
    scan2_k<<<1024, 256, 0, stream>>>(slotB, slotC, Hin, slotA, hT);

    // outp = hs@Wout + bout (-> slotB); x_ = gelu(outp@W1+b1) (-> slotC);
    // s = x_@W2 + b2 + outp -> f32 in d_out
    gemm8_k<<<dim3(64, 4), 512, 0, stream>>>(slotA, WoutT, bout, nullptr, nullptr,
                                             slotB, nullptr, nullptr, 2);
    gemm8_k<<<dim3(64, 4), 512, 0, stream>>>(slotB, W1T,   b1,   nullptr, nullptr,
                                             slotC, nullptr, nullptr, 3);
    gemm8_k<<<dim3(64, 4), 512, 0, stream>>>(slotC, W2T,   b2,   nullptr, slotB,
                                             nullptr, nullptr, out, 4);

    ln_k<<<16384, 256, 0, stream>>>(out, ln_g, ln_b);
}